// Round 1
// baseline (468.533 us; speedup 1.0000x reference)
//
#include <hip/hip_runtime.h>
#include <cstdint>

typedef unsigned short u16;
typedef unsigned long long u64;

__device__ __forceinline__ u16 f2b(float f){
  union { float f; uint32_t i; } v; v.f = f;
  uint32_t r = v.i + 0x7FFFu + ((v.i >> 16) & 1u);   // RNE
  return (u16)(r >> 16);
}
__device__ __forceinline__ float b2f(u16 u){
  union { uint32_t i; float f; } v; v.i = ((uint32_t)u) << 16; return v.f;
}
__device__ __forceinline__ float sigmoidf(float x){ return 1.0f / (1.0f + __expf(-x)); }

__device__ __forceinline__ void gl_lds4(const void* g, void* l){
  __builtin_amdgcn_global_load_lds((const __attribute__((address_space(1))) void*)g,
                                   (__attribute__((address_space(3))) void*)l, 4, 0, 0);
}

// ---- K1a: PURE STREAMING. One wave = one 1024-col mask chunk: 8(16) float4
// loads, 16 ballots, store 16 u64 bitmask words. No gathers -> waves stream
// at full duty cycle (HBM-bound). Aux blocks (bitOp/ghat/packing) unchanged.
__global__ __launch_bounds__(256) void k_stream(
    const float* __restrict__ ww, const float* __restrict__ wem,
    const float* __restrict__ d0, const float* __restrict__ d1,
    const float* __restrict__ wes, const float* __restrict__ wop,
    const float* __restrict__ nh, const float* __restrict__ Wg, const float* __restrict__ bg,
    const float* __restrict__ Wf, const float* __restrict__ Wupd, const float* __restrict__ Wo,
    u64* __restrict__ bits, u64* __restrict__ bitOp, float* __restrict__ ghat,
    uint32_t* __restrict__ pkWf, uint32_t* __restrict__ pkWu, uint32_t* __restrict__ pkWo){
  int tid = threadIdx.x;
  if (blockIdx.x >= 12544){
    int aux = blockIdx.x - 12544;
    if (aux == 16){                               // ghat
      if (tid < 128){
        int b = tid >> 6, h = tid & 63;
        float g = bg[h];
        for (int d = 0; d < 64; ++d) g += nh[b*64 + d] * Wg[d*64 + h];
        float ss = g * g;
        #pragma unroll
        for (int o = 32; o > 0; o >>= 1) ss += __shfl_xor(ss, o, 64);
        ghat[b*64 + h] = g / (sqrtf(ss) + 1e-30f);
      }
      return;
    }
    for (int k = tid; k < 1024; k += 256){        // bf16-pair weight packing
      int i = aux*1024 + k;                       // 0..16383
      const float* src; uint32_t* dst; int li;
      if (i < 8192){ src = Wf; dst = pkWf; li = i; }
      else if (i < 14336){ src = Wupd; dst = pkWu; li = i - 8192; }
      else { src = Wo; dst = pkWo; li = i - 14336; }
      int k2 = li >> 6, ln = li & 63;
      dst[li] = (uint32_t)f2b(src[(2*k2)*64 + ln]) | ((uint32_t)f2b(src[(2*k2+1)*64 + ln]) << 16);
    }
    return;
  }
  int wave = tid >> 6, lane = tid & 63;
  int wid = blockIdx.x*4 + wave;
  if (wid >= 49152){                              // wes & wop -> bitOp[n][o>>6]
    int ng0 = (wid - 49152) * 8;
    #pragma unroll
    for (int i = 0; i < 8; ++i){
      int n = ng0 + i;
      float vx = wop[(size_t)n*128 + lane];
      float vy = wop[(size_t)n*128 + 64 + lane];
      float e  = wes[n];
      u64 m0 = __ballot((e != 0.f) && (vx != 0.f));
      u64 m1 = __ballot((e != 0.f) && (vy != 0.f));
      if (lane == 0) bitOp[(size_t)n*2]     = m0;
      if (lane == 1) bitOp[(size_t)n*2 + 1] = m1;
    }
    return;
  }
  // ---- mask chunk -> 16 ballot words
  const float *A, *B;
  bool two;
  if (wid < 32768){                               // big: row = b*4096+n, 4 chunks
    int row = wid >> 2, chunk = wid & 3;
    A = ww  + (size_t)row*4096 + chunk*1024;
    B = wem + (size_t)row*4096 + chunk*1024;
    two = true;
  } else {                                        // dep: rowp<4096 -> d0, else d1
    int idx = wid - 32768;
    int rowp = idx >> 1, chunk = idx & 1;
    if (rowp < 4096) A = d0 + (size_t)rowp*2048 + chunk*1024;
    else { int rr = rowp - 4096; A = d1 + (size_t)rr*2048 + chunk*1024; }
    B = A; two = false;
  }
  const float4* ap = (const float4*)A + lane;
  const float4* bp = (const float4*)B + lane;
  float4 a0 = ap[0], a1 = ap[64], a2 = ap[128], a3 = ap[192];
  float4 b0, b1, b2, b3;
  if (two){ b0 = bp[0]; b1 = bp[64]; b2 = bp[128]; b3 = bp[192]; }
  else    { b0 = a0;    b1 = a1;     b2 = a2;      b3 = a3; }
  u64 myw = 0;
#define B4(i, va, vb) { \
  u64 m0 = __ballot((va.x != 0.f) && (vb.x != 0.f)); \
  u64 m1 = __ballot((va.y != 0.f) && (vb.y != 0.f)); \
  u64 m2 = __ballot((va.z != 0.f) && (vb.z != 0.f)); \
  u64 m3 = __ballot((va.w != 0.f) && (vb.w != 0.f)); \
  if (lane == (i)*4 + 0) myw = m0; \
  if (lane == (i)*4 + 1) myw = m1; \
  if (lane == (i)*4 + 2) myw = m2; \
  if (lane == (i)*4 + 3) myw = m3; }
  B4(0, a0, b0) B4(1, a1, b1) B4(2, a2, b2) B4(3, a3, b3)
#undef B4
  if (lane < 16) bits[(size_t)wid*16 + lane] = myw;
}

// ---- K1b: GATHER from bitmasks. Queue-compact nonzero cols, then gather
// w-rows (L2-resident) with padded 8-deep DOUBLE-BUFFERED batches and counted
// vmcnt(8) waits (never drain to 0 in steady state); predicated accumulation
// removes the serial dependent-load tail entirely.
__global__ __launch_bounds__(256) void k_gather(
    const u64* __restrict__ bits,
    const float* __restrict__ w0, const float* __restrict__ w1,
    u16* __restrict__ psumB, int* __restrict__ pcntB,
    u16* __restrict__ psumD, int* __restrict__ pcntD){
  __shared__ int q[4][272];                       // 272*4 B = 1088 (16B aligned rows)
  __shared__ float rows[4][2][8][64];             // 16 KB, double-buffered 8-deep
  int tid = threadIdx.x, wave = tid >> 6, lane = tid & 63;
  int wid = blockIdx.x*4 + wave;
  const float *srcA, *srcB;
  int jbase, thresh;
  u16* ps; int* pc;
  if (wid < 32768){                               // big: row = b*4096+n, 4 chunks
    int row = wid >> 2, chunk = wid & 3;
    int b = row >> 12;
    srcA = w0 + (size_t)b*131072 + lane;
    srcB = w1 + (size_t)b*131072 - 131072 + lane;
    jbase = chunk*1024; thresh = 2048;
    ps = psumB + (size_t)wid*64; pc = pcntB + wid;
  } else {                                        // dep
    int idx = wid - 32768;
    int rowp = idx >> 1, chunk = idx & 1;
    if (rowp < 4096){
      int b = rowp >> 11;
      srcA = w0 + (size_t)b*131072 + lane;
    } else {
      int rr = rowp - 4096, b = rr >> 11;
      srcA = w1 + (size_t)b*131072 + lane;
    }
    srcB = srcA;
    jbase = chunk*1024; thresh = 4096;            // never hits srcB
    ps = psumD + (size_t)idx*64; pc = pcntD + idx;
  }
  u64 myw = (lane < 16) ? bits[(size_t)wid*16 + lane] : 0ULL;
  // ---- compact nonzero chunk-cols into LDS queue
  int c = __popcll(myw);
  int pre = c;
  #pragma unroll
  for (int off = 1; off < 64; off <<= 1){
    int t = __shfl_up(pre, off, 64);
    if (lane >= off) pre += t;
  }
  int total = __shfl(pre, 63, 64);
  int base = pre - c;
  int colhi = (lane >> 2) * 256 + (lane & 3);
  u64 m = myw;
  while (m){
    int p = __builtin_ctzll(m); m &= m - 1;
    q[wave][base++] = colhi + p*4;
  }
  // ---- pad queue to multiple of 8 with col 0 (valid addr; contribution masked)
  int totP = (total + 7) & ~7;
  if (lane < totP - total) q[wave][total + lane] = 0;
  float acc = 0.f;
  int nb = totP >> 3;
#define GPJ(qv) (((jbase + (qv)) < thresh ? srcA : srcB) + (size_t)(jbase + (qv))*64)
#define ISSUE(bi, bsel) { \
  int4 c0 = *(const int4*)&q[wave][(bi)*8]; \
  int4 c1 = *(const int4*)&q[wave][(bi)*8 + 4]; \
  gl_lds4(GPJ(c0.x), &rows[wave][bsel][0][0]); \
  gl_lds4(GPJ(c0.y), &rows[wave][bsel][1][0]); \
  gl_lds4(GPJ(c0.z), &rows[wave][bsel][2][0]); \
  gl_lds4(GPJ(c0.w), &rows[wave][bsel][3][0]); \
  gl_lds4(GPJ(c1.x), &rows[wave][bsel][4][0]); \
  gl_lds4(GPJ(c1.y), &rows[wave][bsel][5][0]); \
  gl_lds4(GPJ(c1.z), &rows[wave][bsel][6][0]); \
  gl_lds4(GPJ(c1.w), &rows[wave][bsel][7][0]); }
  if (nb > 0){
    ISSUE(0, 0)
    if (nb > 1) ISSUE(1, 1)
    for (int b = 0; b < nb; ++b){
      if (b + 1 < nb){ asm volatile("s_waitcnt vmcnt(8)" ::: "memory"); }
      else           { asm volatile("s_waitcnt vmcnt(0)" ::: "memory"); }
      int bs = b & 1;
      #pragma unroll
      for (int r = 0; r < 8; ++r){
        float v = rows[wave][bs][r][lane];
        acc += (b*8 + r < total) ? v : 0.f;       // uniform predicate -> cndmask
      }
      if (b + 2 < nb){
        asm volatile("s_waitcnt lgkmcnt(0)" ::: "memory");  // rows reads done before overwrite
        ISSUE(b + 2, bs)
      }
    }
  }
#undef ISSUE
#undef GPJ
  ps[lane] = f2b(acc);
  if (lane == 0) pc[0] = total;
}

// ---- K2: combine partials + linear transform + c*bias + l2n (unchanged)
__global__ __launch_bounds__(256) void k_fin(
    const u16* __restrict__ psumB, const int* __restrict__ pcntB,
    const u16* __restrict__ psumD, const int* __restrict__ pcntD,
    const float* __restrict__ Wwk, const float* __restrict__ bwk,
    const float* __restrict__ Wws, const float* __restrict__ bws,
    u16* __restrict__ wwkn, u16* __restrict__ wwsn){
  __shared__ float sWk[4096], sWs[4096];
  int tid = threadIdx.x, lane = tid & 63, wave = tid >> 6;
  for (int i = tid; i < 1024; i += 256){
    ((float4*)sWk)[i] = ((const float4*)Wwk)[i];
    ((float4*)sWs)[i] = ((const float4*)Wws)[i];
  }
  __syncthreads();
  int wid = blockIdx.x*4 + wave;
  float S; float y; const float* sW; u16* outp; size_t oidx;
  if (wid < 8192){                                // big rows (word_w_k)
    S = b2f(psumB[((size_t)wid*4 + 0)*64 + lane]) + b2f(psumB[((size_t)wid*4 + 1)*64 + lane])
      + b2f(psumB[((size_t)wid*4 + 2)*64 + lane]) + b2f(psumB[((size_t)wid*4 + 3)*64 + lane]);
    int T = pcntB[wid*4] + pcntB[wid*4 + 1] + pcntB[wid*4 + 2] + pcntB[wid*4 + 3];
    y = (float)T * bwk[lane]; sW = sWk; outp = wwkn; oidx = wid;
  } else {                                        // dep rows (word_w_s)
    int rp = wid - 8192;
    S = b2f(psumD[((size_t)rp*2 + 0)*64 + lane]) + b2f(psumD[((size_t)rp*2 + 1)*64 + lane]);
    int T = pcntD[rp*2] + pcntD[rp*2 + 1];
    y = (float)T * bws[lane]; sW = sWs; outp = wwsn;
    int b, n;
    if (rp < 4096){ b = rp >> 11; n = rp & 2047; }
    else { int rr = rp - 4096; b = rr >> 11; n = 2048 + (rr & 2047); }
    oidx = (size_t)b*4096 + n;
  }
  #pragma unroll 8
  for (int d = 0; d < 64; ++d) y += __shfl(S, d, 64) * sW[d*64 + lane];
  float ss = y * y;
  #pragma unroll
  for (int o = 32; o > 0; o >>= 1) ss += __shfl_xor(ss, o, 64);
  outp[oidx*64 + lane] = f2b(y / (sqrtf(ss) + 1e-30f));
}

// ---- K3: gate + update + Wo projection (unchanged)
__global__ __launch_bounds__(256, 2) void k_update(
    const float* __restrict__ w0, const float* __restrict__ w1,
    const float* __restrict__ gw, const float* __restrict__ ghat,
    const u16* __restrict__ wwkn, const u16* __restrict__ wwsn,
    const uint32_t* __restrict__ pkWf, const uint32_t* __restrict__ pkWu,
    const uint32_t* __restrict__ pkWo,
    const float* __restrict__ bf, const float* __restrict__ bupd, const float* __restrict__ bo,
    float* __restrict__ out, float* __restrict__ WUo){
  __shared__ uint32_t pWf[8192];    // 32 KB
  __shared__ uint32_t pWu[6144];    // 24 KB
  __shared__ uint32_t pWo[2048];    // 8 KB
  __shared__ float xsh[4][256];     // 4 KB
  int tid = threadIdx.x;
  for (int i = tid; i < 2048; i += 256) ((uint4*)pWf)[i] = ((const uint4*)pkWf)[i];
  for (int i = tid; i < 1536; i += 256) ((uint4*)pWu)[i] = ((const uint4*)pkWu)[i];
  for (int i = tid; i < 512;  i += 256) ((uint4*)pWo)[i] = ((const uint4*)pkWo)[i];
  __syncthreads();
  int lane = tid & 63, wave = tid >> 6;
  float bff = bf[lane], bup = bupd[lane], boo = bo[lane];
  float aw[4], wgv[4], wk[4], wsv[4];
  #pragma unroll
  for (int t = 0; t < 4; ++t){
    int row = blockIdx.x*4 + wave + t*2048;
    int b = row >> 12, n = row & 4095;
    aw[t] = (n < 2048) ? w0[((size_t)(b*2048 + n))*64 + lane]
                       : w1[((size_t)(b*2048 + n - 2048))*64 + lane];
    float gvv = gw[b*4096 + n];
    wgv[t] = (gvv != 0.f) ? ghat[b*64 + lane] : 0.f;
    wk[t]  = b2f(wwkn[(size_t)row*64 + lane]);
    wsv[t] = b2f(wwsn[(size_t)row*64 + lane]);
  }
  #pragma unroll
  for (int t = 0; t < 4; ++t){
    int row = blockIdx.x*4 + wave + t*2048;
    int b = row >> 12, n = row & 4095;
    xsh[wave][lane] = aw[t]; xsh[wave][64 + lane] = wgv[t];
    xsh[wave][128 + lane] = wk[t]; xsh[wave][192 + lane] = wsv[t];
    float f = bff, u = bup;
    #pragma unroll 8
    for (int k2 = 0; k2 < 32; ++k2){
      float2 xv = *(const float2*)&xsh[wave][2*k2];
      uint32_t wf = pWf[k2*64 + lane];
      f += xv.x * b2f((u16)wf) + xv.y * b2f((u16)(wf >> 16));
    }
    #pragma unroll 8
    for (int k2 = 32; k2 < 128; ++k2){
      float2 xv = *(const float2*)&xsh[wave][2*k2];
      uint32_t wf = pWf[k2*64 + lane];
      uint32_t wu = pWu[(k2 - 32)*64 + lane];
      f += xv.x * b2f((u16)wf) + xv.y * b2f((u16)(wf >> 16));
      u += xv.x * b2f((u16)wu) + xv.y * b2f((u16)(wu >> 16));
    }
    f = sigmoidf(f);
    u = fmaxf(u, 0.f);
    float wu = fmaxf(f, 0.2f) * aw[t] + (1.f - f) * u;
    out[((size_t)b*4224 + n)*64 + lane] = wu;
    float o = boo;
    #pragma unroll 8
    for (int k2 = 0; k2 < 32; ++k2){
      uint32_t wo2 = pWo[k2*64 + lane];
      o += __shfl(wu, 2*k2, 64) * b2f((u16)wo2) + __shfl(wu, 2*k2 + 1, 64) * b2f((u16)(wo2 >> 16));
    }
    WUo[(size_t)row*64 + lane] = o;
  }
}

// ---- K4: fused op aggregation + epilogue (unchanged). One block per (b,o).
__global__ __launch_bounds__(256) void k_opfin(
    const u64* __restrict__ bitOp, const float* __restrict__ WUo,
    const float* __restrict__ opE,
    const float* __restrict__ Wf2, const float* __restrict__ bf2,
    const float* __restrict__ Wout, const float* __restrict__ bout,
    float* __restrict__ out){
  __shared__ float sW2[8192];   // 32 KB
  __shared__ float sWo[4096];   // 16 KB
  __shared__ int q[4][96];
  __shared__ float sacc[4][64];
  __shared__ int scnt[4];
  __shared__ float xsh[128];
  int tid = threadIdx.x, lane = tid & 63, wave = tid >> 6;
  for (int i = tid; i < 2048; i += 256) ((float4*)sW2)[i] = ((const float4*)Wf2)[i];
  for (int i = tid; i < 1024; i += 256) ((float4*)sWo)[i] = ((const float4*)Wout)[i];
  int rowIdx = blockIdx.x;                      // b*128 + o
  int b = rowIdx >> 7, o = rowIdx & 127;
  int wrd = o >> 6, bit = o & 63;
  const u64* bp = bitOp + (size_t)b*8192 + (size_t)wave*2048 + wrd;
  u64 lt = (1ULL << lane) - 1ULL;
  u64 vv[16];
  #pragma unroll
  for (int it = 0; it < 16; ++it) vv[it] = bp[(size_t)(it*64 + lane)*2];
  int cnt = 0;
  #pragma unroll
  for (int it = 0; it < 16; ++it){
    bool nz = (vv[it] >> bit) & 1ULL;
    u64 m = __ballot(nz);
    if (nz) q[wave][cnt + (int)__popcll(m & lt)] = wave*1024 + it*64 + lane;
    cnt += (int)__popcll(m);
  }
  const float* Xb = WUo + (size_t)b*4096*64 + lane;
  float acc = 0.f;
  int i = 0;
  for (; i + 8 <= cnt; i += 8){
    int4 c0 = *(const int4*)&q[wave][i];
    int4 c1 = *(const int4*)&q[wave][i + 4];
    float v0 = Xb[(size_t)c0.x*64], v1 = Xb[(size_t)c0.y*64];
    float v2 = Xb[(size_t)c0.z*64], v3 = Xb[(size_t)c0.w*64];
    float v4 = Xb[(size_t)c1.x*64], v5 = Xb[(size_t)c1.y*64];
    float v6 = Xb[(size_t)c1.z*64], v7 = Xb[(size_t)c1.w*64];
    acc += ((v0 + v1) + (v2 + v3)) + ((v4 + v5) + (v6 + v7));
  }
  for (; i < cnt; ++i) acc += Xb[(size_t)q[wave][i]*64];
  sacc[wave][lane] = acc;
  if (lane == 0) scnt[wave] = cnt;
  __syncthreads();
  if (wave == 0){
    float t = sacc[0][lane] + sacc[1][lane] + sacc[2][lane] + sacc[3][lane];
    float deg = (float)(scnt[0] + scnt[1] + scnt[2] + scnt[3]);
    float wo = t / (deg + 1e-30f);
    float e  = opE[(size_t)rowIdx*64 + lane];
    xsh[lane] = e; xsh[64 + lane] = wo;
    float f = bf2[lane], u = bout[lane];
    #pragma unroll 8
    for (int k = 0; k < 128; ++k) f += xsh[k] * sW2[k*64 + lane];
    #pragma unroll 8
    for (int d = 0; d < 64; ++d)  u += xsh[64 + d] * sWo[d*64 + lane];
    f = sigmoidf(f);
    u = fmaxf(u, 0.f);
    float res = fmaxf(f, 0.2f) * e + (1.f - f) * u;
    out[((size_t)b*4224 + 4096 + o)*64 + lane] = res;
  }
}

extern "C" void kernel_launch(void* const* d_in, const int* in_sizes, int n_in,
                              void* d_out, int out_size, void* d_ws, size_t ws_size,
                              hipStream_t stream){
  const float* w0   = (const float*)d_in[0];
  const float* w1   = (const float*)d_in[1];
  const float* nh   = (const float*)d_in[2];
  const float* opE  = (const float*)d_in[3];
  const float* wes  = (const float*)d_in[4];
  const float* wem  = (const float*)d_in[5];
  const float* wop  = (const float*)d_in[6];
  const float* ww   = (const float*)d_in[7];
  const float* d0   = (const float*)d_in[8];
  const float* d1   = (const float*)d_in[9];
  const float* gw   = (const float*)d_in[10];
  const float* Wg   = (const float*)d_in[11];
  const float* bg   = (const float*)d_in[12];
  const float* Wwk  = (const float*)d_in[13];
  const float* bwk  = (const float*)d_in[14];
  const float* Wws  = (const float*)d_in[15];
  const float* bws  = (const float*)d_in[16];
  const float* Wo   = (const float*)d_in[17];
  const float* bo   = (const float*)d_in[18];
  const float* Wupd = (const float*)d_in[19];
  const float* bupd = (const float*)d_in[20];
  const float* Wf   = (const float*)d_in[21];
  const float* bf   = (const float*)d_in[22];
  const float* Wf2  = (const float*)d_in[23];
  const float* bf2  = (const float*)d_in[24];
  const float* Wout = (const float*)d_in[25];
  const float* bout = (const float*)d_in[26];

  float* ws    = (float*)d_ws;
  float* ghat  = ws;                             // 128
  uint32_t* pkWf = (uint32_t*)(ws + 128);        // 8192 u32
  uint32_t* pkWu = (uint32_t*)(ws + 8320);       // 6144 u32
  uint32_t* pkWo = (uint32_t*)(ws + 14464);      // 2048 u32
  u64*  bitOp  = (u64*)(ws + 16512);             // 16384 u64 (32768 f32)
  u16*  psumB  = (u16*)(ws + 49280);             // 32768 chunks x 64 u16 (1048576 f32)
  int*  pcntB  = (int*)(ws + 1097856);           // 32768 int
  u16*  psumD  = (u16*)(ws + 1130624);           // 16384 chunks x 64 u16 (524288 f32)
  int*  pcntD  = (int*)(ws + 1654912);           // 16384 int
  u16*  wwkn   = (u16*)(ws + 1671296);           // 524288 u16 (262144 f32)
  u16*  wwsn   = (u16*)(ws + 1933440);           // 524288 u16
  float* WUo   = ws + 2195584;                   // 524288 f32
  // bits: 49152 chunks x 16 u64 = 6 MB, OVERLAID on [wwkn..WUo_end) + 2 MB ext.
  // Lifetime: written by k_stream, read by k_gather, DEAD before k_fin writes
  // wwkn/wwsn and k_update writes WUo (strictly later in stream order).
  u64*  bits   = (u64*)(ws + 1671296);           // 786432 u64 (1572864 f32) -> ws end 3244160 f32
  float* out   = (float*)d_out;

  k_stream<<<12561, 256, 0, stream>>>(ww, wem, d0, d1, wes, wop,
                                      nh, Wg, bg, Wf, Wupd, Wo,
                                      bits, bitOp, ghat, pkWf, pkWu, pkWo);
  k_gather<<<12288, 256, 0, stream>>>(bits, w0, w1,
                                      psumB, pcntB, psumD, pcntD);
  k_fin<<<4096, 256, 0, stream>>>(psumB, pcntB, psumD, pcntD,
                                  Wwk, bwk, Wws, bws, wwkn, wwsn);
  k_update<<<512, 256, 0, stream>>>(w0, w1, gw, ghat, wwkn, wwsn,
                                    pkWf, pkWu, pkWo, bf, bupd, bo, out, WUo);
  k_opfin<<<256, 256, 0, stream>>>(bitOp, WUo, opE, Wf2, bf2, Wout, bout, out);
}

// Round 2
// 448.944 us; speedup vs baseline: 1.0436x; 1.0436x over previous
//
#include <hip/hip_runtime.h>
#include <cstdint>

typedef unsigned short u16;
typedef unsigned long long u64;

__device__ __forceinline__ u16 f2b(float f){
  union { float f; uint32_t i; } v; v.f = f;
  uint32_t r = v.i + 0x7FFFu + ((v.i >> 16) & 1u);   // RNE
  return (u16)(r >> 16);
}
__device__ __forceinline__ float b2f(u16 u){
  union { uint32_t i; float f; } v; v.i = ((uint32_t)u) << 16; return v.f;
}
__device__ __forceinline__ float sigmoidf(float x){ return 1.0f / (1.0f + __expf(-x)); }

__device__ __forceinline__ void gl_lds4(const void* g, void* l){
  __builtin_amdgcn_global_load_lds((const __attribute__((address_space(1))) void*)g,
                                   (__attribute__((address_space(3))) void*)l, 4, 0, 0);
}

// Compute mask-stream pointers for task t (0..49151).
__device__ __forceinline__ void mask_ptrs(int t,
    const float* ww, const float* wem, const float* d0, const float* d1,
    const float4** ap, const float4** bp, bool* two){
  if (t < 32768){                                  // big: row = t>>2, 4 chunks/row
    int row = t >> 2, chunk = t & 3;
    *ap = (const float4*)(ww  + (size_t)row*4096 + chunk*1024);
    *bp = (const float4*)(wem + (size_t)row*4096 + chunk*1024);
    *two = true;
  } else {                                         // dep: rowp<4096 -> d0 else d1
    int idx = t - 32768, rowp = idx >> 1, chunk = idx & 1;
    const float* base;
    if (rowp < 4096) base = d0 + (size_t)rowp*2048 + chunk*1024;
    else { int rr = rowp - 4096; base = d1 + (size_t)rr*2048 + chunk*1024; }
    *ap = (const float4*)base; *bp = (const float4*)base; *two = false;
  }
}

// ---- K1: PERSISTENT fused mask-stream + gather. 2048 work blocks x 4 waves;
// each wave handles 6 chunk-tasks (t = wid + it*8192). Per iteration the NEXT
// task's mask loads are issued into registers BEFORE the current task's
// latency-heavy gather phase -> HBM stream stays fed at full duty cycle.
// Aux blocks (wop bits / weight packing / ghat) trail the grid.
__global__ __launch_bounds__(256) void k_mask(
    const float* __restrict__ ww, const float* __restrict__ wem,
    const float* __restrict__ d0, const float* __restrict__ d1,
    const float* __restrict__ wes, const float* __restrict__ wop,
    const float* __restrict__ w0, const float* __restrict__ w1,
    const float* __restrict__ nh, const float* __restrict__ Wg, const float* __restrict__ bg,
    const float* __restrict__ Wf, const float* __restrict__ Wupd, const float* __restrict__ Wo,
    u16* __restrict__ psumB, int* __restrict__ pcntB,
    u16* __restrict__ psumD, int* __restrict__ pcntD,
    u64* __restrict__ bitOp, float* __restrict__ ghat,
    uint32_t* __restrict__ pkWf, uint32_t* __restrict__ pkWu, uint32_t* __restrict__ pkWo){
  __shared__ int q[4][272];
  __shared__ float rows[4][8][64];                 // 8 KB, 8-deep gather batch
  int tid = threadIdx.x, wave = tid >> 6, lane = tid & 63;
  int bid = blockIdx.x;
  if (bid >= 2048){
    if (bid >= 2304){
      int aux = bid - 2304;                        // 0..16
      if (aux == 16){                              // ghat
        if (tid < 128){
          int b = tid >> 6, h = tid & 63;
          float g = bg[h];
          for (int d = 0; d < 64; ++d) g += nh[b*64 + d] * Wg[d*64 + h];
          float ss = g * g;
          #pragma unroll
          for (int o = 32; o > 0; o >>= 1) ss += __shfl_xor(ss, o, 64);
          ghat[b*64 + h] = g / (sqrtf(ss) + 1e-30f);
        }
        return;
      }
      for (int k = tid; k < 1024; k += 256){       // bf16-pair weight packing
        int i = aux*1024 + k;                      // 0..16383
        const float* src; uint32_t* dst; int li;
        if (i < 8192){ src = Wf; dst = pkWf; li = i; }
        else if (i < 14336){ src = Wupd; dst = pkWu; li = i - 8192; }
        else { src = Wo; dst = pkWo; li = i - 14336; }
        int k2 = li >> 6, ln = li & 63;
        dst[li] = (uint32_t)f2b(src[(2*k2)*64 + ln]) | ((uint32_t)f2b(src[(2*k2+1)*64 + ln]) << 16);
      }
      return;
    }
    // wop bits: wes & wop -> bitOp[n][o>>6]
    int w = (bid - 2048)*4 + wave;                 // 0..1023
    int ng0 = w * 8;
    #pragma unroll
    for (int i = 0; i < 8; ++i){
      int n = ng0 + i;
      float vx = wop[(size_t)n*128 + lane];
      float vy = wop[(size_t)n*128 + 64 + lane];
      float e  = wes[n];
      u64 m0 = __ballot((e != 0.f) && (vx != 0.f));
      u64 m1 = __ballot((e != 0.f) && (vy != 0.f));
      if (lane == 0) bitOp[(size_t)n*2]     = m0;
      if (lane == 1) bitOp[(size_t)n*2 + 1] = m1;
    }
    return;
  }
  int wid = bid*4 + wave;                          // 0..8191
  // ---- prologue: issue masks for task 0 (always a big task: wid < 8192)
  const float4 *ap, *bp; bool two;
  mask_ptrs(wid, ww, wem, d0, d1, &ap, &bp, &two);
  float4 a0 = ap[lane], a1 = ap[64 + lane], a2 = ap[128 + lane], a3 = ap[192 + lane];
  float4 b0 = {0,0,0,0}, b1 = {0,0,0,0}, b2 = {0,0,0,0}, b3 = {0,0,0,0};
  if (two){ b0 = bp[lane]; b1 = bp[64 + lane]; b2 = bp[128 + lane]; b3 = bp[192 + lane]; }

  for (int it = 0; it < 6; ++it){
    int t = wid + it*8192;
    // ---- gather params for current task (wave-uniform scalars)
    const float *srcA, *srcB;
    int jbase, thresh;
    u16* ps; int* pc;
    if (t < 32768){
      int row = t >> 2, chunk = t & 3;
      int b = row >> 12;
      srcA = w0 + (size_t)b*131072 + lane;
      srcB = w1 + (size_t)b*131072 - 131072 + lane;
      jbase = chunk*1024; thresh = 2048;
      ps = psumB + (size_t)t*64; pc = pcntB + t;
    } else {
      int idx = t - 32768, rowp = idx >> 1, chunk = idx & 1;
      if (rowp < 4096){
        int b = rowp >> 11;
        srcA = w0 + (size_t)b*131072 + lane;
      } else {
        int rr = rowp - 4096, b = rr >> 11;
        srcA = w1 + (size_t)b*131072 + lane;
      }
      srcB = srcA;
      jbase = chunk*1024; thresh = 4096;           // never hits srcB
      ps = psumD + (size_t)idx*64; pc = pcntD + idx;
    }
    // ---- issue NEXT task's mask loads (in flight across the gather phase)
    float4 an0 = {0,0,0,0}, an1 = {0,0,0,0}, an2 = {0,0,0,0}, an3 = {0,0,0,0};
    float4 bn0 = {0,0,0,0}, bn1 = {0,0,0,0}, bn2 = {0,0,0,0}, bn3 = {0,0,0,0};
    bool twon = false;
    if (it < 5){
      const float4 *apn, *bpn;
      mask_ptrs(t + 8192, ww, wem, d0, d1, &apn, &bpn, &twon);
      an0 = apn[lane]; an1 = apn[64 + lane]; an2 = apn[128 + lane]; an3 = apn[192 + lane];
      if (twon){ bn0 = bpn[lane]; bn1 = bpn[64 + lane]; bn2 = bpn[128 + lane]; bn3 = bpn[192 + lane]; }
    }
    // ---- ballot current masks -> 16 words (lanes 0..15 hold one each)
    u64 myw = 0;
#define B4(i, va, vb) { \
  u64 m0 = __ballot((va.x != 0.f) && (!two || (vb.x != 0.f))); \
  u64 m1 = __ballot((va.y != 0.f) && (!two || (vb.y != 0.f))); \
  u64 m2 = __ballot((va.z != 0.f) && (!two || (vb.z != 0.f))); \
  u64 m3 = __ballot((va.w != 0.f) && (!two || (vb.w != 0.f))); \
  if (lane == (i)*4 + 0) myw = m0; \
  if (lane == (i)*4 + 1) myw = m1; \
  if (lane == (i)*4 + 2) myw = m2; \
  if (lane == (i)*4 + 3) myw = m3; }
    B4(0, a0, b0) B4(1, a1, b1) B4(2, a2, b2) B4(3, a3, b3)
#undef B4
    // ---- compact nonzero chunk-cols into LDS queue
    int c = __popcll(myw);
    int pre = c;
    #pragma unroll
    for (int off = 1; off < 64; off <<= 1){
      int tt = __shfl_up(pre, off, 64);
      if (lane >= off) pre += tt;
    }
    int total = __shfl(pre, 63, 64);
    int base = pre - c;
    int colhi = (lane >> 2) * 256 + (lane & 3);
    u64 m = myw;
    while (m){
      int p = __builtin_ctzll(m); m &= m - 1;
      q[wave][base++] = colhi + p*4;
    }
    // pad queue to multiple of 8 (col 0 = valid addr; contribution predicated off)
    int totP = (total + 7) & ~7;
    if (lane < totP - total) q[wave][total + lane] = 0;
    // ---- gather w-rows (L2-resident) in 8-deep batches
    float acc = 0.f;
#define GPJ(qv) (((jbase + (qv)) < thresh ? srcA : srcB) + (size_t)(jbase + (qv))*64)
    for (int b8 = 0; b8 < totP; b8 += 8){
      int4 c0 = *(const int4*)&q[wave][b8];
      int4 c1 = *(const int4*)&q[wave][b8 + 4];
      gl_lds4(GPJ(c0.x), &rows[wave][0][0]);
      gl_lds4(GPJ(c0.y), &rows[wave][1][0]);
      gl_lds4(GPJ(c0.z), &rows[wave][2][0]);
      gl_lds4(GPJ(c0.w), &rows[wave][3][0]);
      gl_lds4(GPJ(c1.x), &rows[wave][4][0]);
      gl_lds4(GPJ(c1.y), &rows[wave][5][0]);
      gl_lds4(GPJ(c1.z), &rows[wave][6][0]);
      gl_lds4(GPJ(c1.w), &rows[wave][7][0]);
      asm volatile("s_waitcnt vmcnt(0)" ::: "memory");
      #pragma unroll
      for (int r = 0; r < 8; ++r){
        float v = rows[wave][r][lane];
        acc += (b8 + r < total) ? v : 0.f;         // uniform predicate -> cndmask
      }
    }
#undef GPJ
    ps[lane] = f2b(acc);
    if (lane == 0) pc[0] = total;
    // ---- rotate next-task masks into current regs
    if (it < 5){
      a0 = an0; a1 = an1; a2 = an2; a3 = an3;
      if (twon){ b0 = bn0; b1 = bn1; b2 = bn2; b3 = bn3; }
      two = twon;
    }
  }
}

// ---- K2: combine partials + linear transform + c*bias + l2n.
// Grid-strided: 1024 blocks x 4 wid-rounds (weights staged in LDS once).
__global__ __launch_bounds__(256) void k_fin(
    const u16* __restrict__ psumB, const int* __restrict__ pcntB,
    const u16* __restrict__ psumD, const int* __restrict__ pcntD,
    const float* __restrict__ Wwk, const float* __restrict__ bwk,
    const float* __restrict__ Wws, const float* __restrict__ bws,
    u16* __restrict__ wwkn, u16* __restrict__ wwsn){
  __shared__ float sWk[4096], sWs[4096];
  int tid = threadIdx.x, lane = tid & 63, wave = tid >> 6;
  for (int i = tid; i < 1024; i += 256){
    ((float4*)sWk)[i] = ((const float4*)Wwk)[i];
    ((float4*)sWs)[i] = ((const float4*)Wws)[i];
  }
  __syncthreads();
  for (int r = 0; r < 4; ++r){
    int wid = blockIdx.x*4 + wave + r*4096;        // 0..16383
    float S; float y; const float* sW; u16* outp; size_t oidx;
    if (wid < 8192){                               // big rows (word_w_k)
      S = b2f(psumB[((size_t)wid*4 + 0)*64 + lane]) + b2f(psumB[((size_t)wid*4 + 1)*64 + lane])
        + b2f(psumB[((size_t)wid*4 + 2)*64 + lane]) + b2f(psumB[((size_t)wid*4 + 3)*64 + lane]);
      int T = pcntB[wid*4] + pcntB[wid*4 + 1] + pcntB[wid*4 + 2] + pcntB[wid*4 + 3];
      y = (float)T * bwk[lane]; sW = sWk; outp = wwkn; oidx = wid;
    } else {                                       // dep rows (word_w_s)
      int rp = wid - 8192;
      S = b2f(psumD[((size_t)rp*2 + 0)*64 + lane]) + b2f(psumD[((size_t)rp*2 + 1)*64 + lane]);
      int T = pcntD[rp*2] + pcntD[rp*2 + 1];
      y = (float)T * bws[lane]; sW = sWs; outp = wwsn;
      int b, n;
      if (rp < 4096){ b = rp >> 11; n = rp & 2047; }
      else { int rr = rp - 4096; b = rr >> 11; n = 2048 + (rr & 2047); }
      oidx = (size_t)b*4096 + n;
    }
    #pragma unroll 8
    for (int d = 0; d < 64; ++d) y += __shfl(S, d, 64) * sW[d*64 + lane];
    float ss = y * y;
    #pragma unroll
    for (int o = 32; o > 0; o >>= 1) ss += __shfl_xor(ss, o, 64);
    outp[oidx*64 + lane] = f2b(y / (sqrtf(ss) + 1e-30f));
  }
}

// ---- K3: gate + update + Wo projection (unchanged)
__global__ __launch_bounds__(256, 2) void k_update(
    const float* __restrict__ w0, const float* __restrict__ w1,
    const float* __restrict__ gw, const float* __restrict__ ghat,
    const u16* __restrict__ wwkn, const u16* __restrict__ wwsn,
    const uint32_t* __restrict__ pkWf, const uint32_t* __restrict__ pkWu,
    const uint32_t* __restrict__ pkWo,
    const float* __restrict__ bf, const float* __restrict__ bupd, const float* __restrict__ bo,
    float* __restrict__ out, float* __restrict__ WUo){
  __shared__ uint32_t pWf[8192];    // 32 KB
  __shared__ uint32_t pWu[6144];    // 24 KB
  __shared__ uint32_t pWo[2048];    // 8 KB
  __shared__ float xsh[4][256];     // 4 KB
  int tid = threadIdx.x;
  for (int i = tid; i < 2048; i += 256) ((uint4*)pWf)[i] = ((const uint4*)pkWf)[i];
  for (int i = tid; i < 1536; i += 256) ((uint4*)pWu)[i] = ((const uint4*)pkWu)[i];
  for (int i = tid; i < 512;  i += 256) ((uint4*)pWo)[i] = ((const uint4*)pkWo)[i];
  __syncthreads();
  int lane = tid & 63, wave = tid >> 6;
  float bff = bf[lane], bup = bupd[lane], boo = bo[lane];
  float aw[4], wgv[4], wk[4], wsv[4];
  #pragma unroll
  for (int t = 0; t < 4; ++t){
    int row = blockIdx.x*4 + wave + t*2048;
    int b = row >> 12, n = row & 4095;
    aw[t] = (n < 2048) ? w0[((size_t)(b*2048 + n))*64 + lane]
                       : w1[((size_t)(b*2048 + n - 2048))*64 + lane];
    float gvv = gw[b*4096 + n];
    wgv[t] = (gvv != 0.f) ? ghat[b*64 + lane] : 0.f;
    wk[t]  = b2f(wwkn[(size_t)row*64 + lane]);
    wsv[t] = b2f(wwsn[(size_t)row*64 + lane]);
  }
  #pragma unroll
  for (int t = 0; t < 4; ++t){
    int row = blockIdx.x*4 + wave + t*2048;
    int b = row >> 12, n = row & 4095;
    xsh[wave][lane] = aw[t]; xsh[wave][64 + lane] = wgv[t];
    xsh[wave][128 + lane] = wk[t]; xsh[wave][192 + lane] = wsv[t];
    float f = bff, u = bup;
    #pragma unroll 8
    for (int k2 = 0; k2 < 32; ++k2){
      float2 xv = *(const float2*)&xsh[wave][2*k2];
      uint32_t wf = pWf[k2*64 + lane];
      f += xv.x * b2f((u16)wf) + xv.y * b2f((u16)(wf >> 16));
    }
    #pragma unroll 8
    for (int k2 = 32; k2 < 128; ++k2){
      float2 xv = *(const float2*)&xsh[wave][2*k2];
      uint32_t wf = pWf[k2*64 + lane];
      uint32_t wu = pWu[(k2 - 32)*64 + lane];
      f += xv.x * b2f((u16)wf) + xv.y * b2f((u16)(wf >> 16));
      u += xv.x * b2f((u16)wu) + xv.y * b2f((u16)(wu >> 16));
    }
    f = sigmoidf(f);
    u = fmaxf(u, 0.f);
    float wu = fmaxf(f, 0.2f) * aw[t] + (1.f - f) * u;
    out[((size_t)b*4224 + n)*64 + lane] = wu;
    float o = boo;
    #pragma unroll 8
    for (int k2 = 0; k2 < 32; ++k2){
      uint32_t wo2 = pWo[k2*64 + lane];
      o += __shfl(wu, 2*k2, 64) * b2f((u16)wo2) + __shfl(wu, 2*k2 + 1, 64) * b2f((u16)(wo2 >> 16));
    }
    WUo[(size_t)row*64 + lane] = o;
  }
}

// ---- K4: fused op aggregation + epilogue (unchanged). One block per (b,o).
__global__ __launch_bounds__(256) void k_opfin(
    const u64* __restrict__ bitOp, const float* __restrict__ WUo,
    const float* __restrict__ opE,
    const float* __restrict__ Wf2, const float* __restrict__ bf2,
    const float* __restrict__ Wout, const float* __restrict__ bout,
    float* __restrict__ out){
  __shared__ float sW2[8192];   // 32 KB
  __shared__ float sWo[4096];   // 16 KB
  __shared__ int q[4][96];
  __shared__ float sacc[4][64];
  __shared__ int scnt[4];
  __shared__ float xsh[128];
  int tid = threadIdx.x, lane = tid & 63, wave = tid >> 6;
  for (int i = tid; i < 2048; i += 256) ((float4*)sW2)[i] = ((const float4*)Wf2)[i];
  for (int i = tid; i < 1024; i += 256) ((float4*)sWo)[i] = ((const float4*)Wout)[i];
  int rowIdx = blockIdx.x;                      // b*128 + o
  int b = rowIdx >> 7, o = rowIdx & 127;
  int wrd = o >> 6, bit = o & 63;
  const u64* bp = bitOp + (size_t)b*8192 + (size_t)wave*2048 + wrd;
  u64 lt = (1ULL << lane) - 1ULL;
  u64 vv[16];
  #pragma unroll
  for (int it = 0; it < 16; ++it) vv[it] = bp[(size_t)(it*64 + lane)*2];
  int cnt = 0;
  #pragma unroll
  for (int it = 0; it < 16; ++it){
    bool nz = (vv[it] >> bit) & 1ULL;
    u64 m = __ballot(nz);
    if (nz) q[wave][cnt + (int)__popcll(m & lt)] = wave*1024 + it*64 + lane;
    cnt += (int)__popcll(m);
  }
  const float* Xb = WUo + (size_t)b*4096*64 + lane;
  float acc = 0.f;
  int i = 0;
  for (; i + 8 <= cnt; i += 8){
    int4 c0 = *(const int4*)&q[wave][i];
    int4 c1 = *(const int4*)&q[wave][i + 4];
    float v0 = Xb[(size_t)c0.x*64], v1 = Xb[(size_t)c0.y*64];
    float v2 = Xb[(size_t)c0.z*64], v3 = Xb[(size_t)c0.w*64];
    float v4 = Xb[(size_t)c1.x*64], v5 = Xb[(size_t)c1.y*64];
    float v6 = Xb[(size_t)c1.z*64], v7 = Xb[(size_t)c1.w*64];
    acc += ((v0 + v1) + (v2 + v3)) + ((v4 + v5) + (v6 + v7));
  }
  for (; i < cnt; ++i) acc += Xb[(size_t)q[wave][i]*64];
  sacc[wave][lane] = acc;
  if (lane == 0) scnt[wave] = cnt;
  __syncthreads();
  if (wave == 0){
    float t = sacc[0][lane] + sacc[1][lane] + sacc[2][lane] + sacc[3][lane];
    float deg = (float)(scnt[0] + scnt[1] + scnt[2] + scnt[3]);
    float wo = t / (deg + 1e-30f);
    float e  = opE[(size_t)rowIdx*64 + lane];
    xsh[lane] = e; xsh[64 + lane] = wo;
    float f = bf2[lane], u = bout[lane];
    #pragma unroll 8
    for (int k = 0; k < 128; ++k) f += xsh[k] * sW2[k*64 + lane];
    #pragma unroll 8
    for (int d = 0; d < 64; ++d)  u += xsh[64 + d] * sWo[d*64 + lane];
    f = sigmoidf(f);
    u = fmaxf(u, 0.f);
    float res = fmaxf(f, 0.2f) * e + (1.f - f) * u;
    out[((size_t)b*4224 + 4096 + o)*64 + lane] = res;
  }
}

extern "C" void kernel_launch(void* const* d_in, const int* in_sizes, int n_in,
                              void* d_out, int out_size, void* d_ws, size_t ws_size,
                              hipStream_t stream){
  const float* w0   = (const float*)d_in[0];
  const float* w1   = (const float*)d_in[1];
  const float* nh   = (const float*)d_in[2];
  const float* opE  = (const float*)d_in[3];
  const float* wes  = (const float*)d_in[4];
  const float* wem  = (const float*)d_in[5];
  const float* wop  = (const float*)d_in[6];
  const float* ww   = (const float*)d_in[7];
  const float* d0   = (const float*)d_in[8];
  const float* d1   = (const float*)d_in[9];
  const float* gw   = (const float*)d_in[10];
  const float* Wg   = (const float*)d_in[11];
  const float* bg   = (const float*)d_in[12];
  const float* Wwk  = (const float*)d_in[13];
  const float* bwk  = (const float*)d_in[14];
  const float* Wws  = (const float*)d_in[15];
  const float* bws  = (const float*)d_in[16];
  const float* Wo   = (const float*)d_in[17];
  const float* bo   = (const float*)d_in[18];
  const float* Wupd = (const float*)d_in[19];
  const float* bupd = (const float*)d_in[20];
  const float* Wf   = (const float*)d_in[21];
  const float* bf   = (const float*)d_in[22];
  const float* Wf2  = (const float*)d_in[23];
  const float* bf2  = (const float*)d_in[24];
  const float* Wout = (const float*)d_in[25];
  const float* bout = (const float*)d_in[26];

  float* ws    = (float*)d_ws;
  float* ghat  = ws;                             // 128
  uint32_t* pkWf = (uint32_t*)(ws + 128);        // 8192 u32
  uint32_t* pkWu = (uint32_t*)(ws + 8320);       // 6144 u32
  uint32_t* pkWo = (uint32_t*)(ws + 14464);      // 2048 u32
  u64*  bitOp  = (u64*)(ws + 16512);             // 16384 u64 (32768 f32)
  u16*  psumB  = (u16*)(ws + 49280);             // 32768 chunks x 64 u16 (1048576 f32)
  int*  pcntB  = (int*)(ws + 1097856);           // 32768 int
  u16*  psumD  = (u16*)(ws + 1130624);           // 16384 chunks x 64 u16 (524288 f32)
  int*  pcntD  = (int*)(ws + 1654912);           // 16384 int
  u16*  wwkn   = (u16*)(ws + 1671296);           // 524288 u16 (262144 f32)
  u16*  wwsn   = (u16*)(ws + 1933440);           // 524288 u16
  float* WUo   = ws + 2195584;                   // 524288 f32 -> ws end 2719872 f32
  float* out   = (float*)d_out;

  k_mask<<<2321, 256, 0, stream>>>(ww, wem, d0, d1, wes, wop, w0, w1,
                                   nh, Wg, bg, Wf, Wupd, Wo,
                                   psumB, pcntB, psumD, pcntD,
                                   bitOp, ghat, pkWf, pkWu, pkWo);
  k_fin<<<1024, 256, 0, stream>>>(psumB, pcntB, psumD, pcntD,
                                  Wwk, bwk, Wws, bws, wwkn, wwsn);
  k_update<<<512, 256, 0, stream>>>(w0, w1, gw, ghat, wwkn, wwsn,
                                    pkWf, pkWu, pkWo, bf, bupd, bo, out, WUo);
  k_opfin<<<256, 256, 0, stream>>>(bitOp, WUo, opE, Wf2, bf2, Wout, bout, out);
}